// Round 7
// baseline (451.097 us; speedup 1.0000x reference)
//
#include <hip/hip_runtime.h>

// Problem constants (from reference)
#define SCREEN_W 1280
#define SCREEN_H 720
#define TILE_L   16
#define NBW      80    // ceil(1280/16)
#define NBH      45    // ceil(720/16)
#define NUM_TILE 3600  // 80*45
#define N_POINTS 32768

#define TOTAL_ITEMS (NUM_TILE * (N_POINTS / 4))   // 29,491,200 uint4 outputs
#define QUARTER     (TOTAL_ITEMS / 4)             // 7,372,800 = 900 * 8192

typedef int v4i __attribute__((ext_vector_type(4)));

// ---------------------------------------------------------------------------
// R11: SINGLE fused kernel = R10's rotated-quad store shape + in-thread AABB.
//
// Evidence driving this design:
//  - R9 direct measurement: this store shape (4 independent 16 B streams,
//    QUARTER apart) runs at 6.0 TB/s with FETCH~0 (mask_quad: 1.888 GB /
//    314 µs). A single 472 MB pass is ~78 µs — at the write roofline.
//  - R4 (one-shot) and R10 (rotated-quad) totals are IDENTICAL (446.5 vs
//    448.8) despite unrelated structures -> the residual ~65 µs is not mask
//    execution; subtraction-decomposition is unreliable (R9's implied-B3 at
//    11 TB/s; harness 15 KB fills taking 299 µs prove duration != work).
//  - Last controllable lever: kernel-boundary count. This kernel fuses
//    aabb (one-time per thread: t = g&8191 is invariant across the 4 stores)
//    -> ONE launch, zero workspace, aabb dispatch + gap eliminated.
//  - Compute headroom proven: R9 measured VALUBusy 32% with this inner loop
//    at 4x store volume; the added ~60 VALU/thread amortize over 4 stores
//    and sit far under the ~87 CU-cycles/store BW budget.
//
// Thread g in [0, QUARTER): items {g, g+Q, g+2Q, g+3Q}, each exactly once.
// Inputs: 3 coalesced float4 loads/thread from 384 KB L2-resident arrays.
// Range semantics identical to the verified aabb_kernel (absmax 0 since R4):
//   overlap_x(xi) <=> (xmin>>4) <= xi < ((xmax+15)>>4), clamp/trunc as ref.
// ---------------------------------------------------------------------------
__global__ void __launch_bounds__(256)
fused_mask_kernel(const float* __restrict__ pos2d,
                  const float* __restrict__ radius,
                  int* __restrict__ out) {
    const int g = blockIdx.x * 256 + (int)threadIdx.x;   // [0, QUARTER)
    const int t = g & 8191;                              // invariant point-group
    const int n = t * 4;                                 // first point index
    const unsigned int tile0 = (unsigned int)g >> 13;    // [0, 900)

    // --- one-time AABB for this thread's 4 points (verbatim R4 semantics) ---
    const float4 p01 = *(const float4*)(pos2d + 2 * n);       // x0 y0 x1 y1
    const float4 p23 = *(const float4*)(pos2d + 2 * n + 4);   // x2 y2 x3 y3
    const float4 r4  = *(const float4*)(radius + n);

    float xs[4] = {p01.x, p01.z, p23.x, p23.z};
    float ys[4] = {p01.y, p01.w, p23.y, p23.w};
    float rs[4] = {r4.x, r4.y, r4.z, r4.w};

    unsigned int xlo[4], xhi[4], ylo[4], yhi[4];
#pragma unroll
    for (int j = 0; j < 4; ++j) {
        float x = xs[j], y = ys[j], rr = rs[j];
        int xmin = (int)fminf(fmaxf(x - rr, 0.0f), (float)SCREEN_W);
        int ymin = (int)fminf(fmaxf(y - rr, 0.0f), (float)SCREEN_H);
        int xmax = (int)fminf(fmaxf(x + rr, 0.0f), (float)SCREEN_W);
        int ymax = (int)fminf(fmaxf(y + rr, 0.0f), (float)SCREEN_H);
        xlo[j] = (unsigned int)(xmin >> 4);          // <= 80
        xhi[j] = (unsigned int)((xmax + 15) >> 4);   // <= 80
        ylo[j] = (unsigned int)(ymin >> 4);          // <= 45
        yhi[j] = (unsigned int)((ymax + 15) >> 4);   // <= 45
    }

    // --- 4 rotated stores: tile steps by +900; all independent, in flight
    //     together before the single end-of-kernel drain ---
#pragma unroll
    for (int k = 0; k < 4; ++k) {
        const unsigned int tile = tile0 + 900u * (unsigned int)k;
        const unsigned int xi = tile / (unsigned int)NBH;   // magic-mul
        const unsigned int yi = tile - xi * (unsigned int)NBH;

        v4i res;
#pragma unroll
        for (int j = 0; j < 4; ++j) {
            res[j] = (xi >= xlo[j] && xi < xhi[j] &&
                      yi >= ylo[j] && yi < yhi[j]) ? 1 : 0;
        }

        *(v4i*)(out + (size_t)(g + k * QUARTER) * 4) = res;
    }
}

extern "C" void kernel_launch(void* const* d_in, const int* in_sizes, int n_in,
                              void* d_out, int out_size, void* d_ws, size_t ws_size,
                              hipStream_t stream) {
    const float* pos2d  = (const float*)d_in[0];
    const float* radius = (const float*)d_in[1];
    int* out = (int*)d_out;

    // ONE launch: 28,800 blocks x 256 threads. No workspace, no aabb pass.
    fused_mask_kernel<<<dim3(QUARTER / 256), dim3(256), 0, stream>>>(pos2d, radius, out);
}